// Round 16
// baseline (56.096 us; speedup 1.0000x reference)
//
#include <hip/hip_runtime.h>
#include <stdint.h>

#define OUTD 4000
#define NP2 4224        // padded N: 22 tiles of 192
#define CC 16
#define WW 48
#define HH 48
#define BB 128
#define KD 768          // C*H contraction depth
#define MD 6144         // B*W rows
#define EPSF 1e-6f

#define BM 192          // 4 batches * 48 w
#define BN 192
#define BKU 64          // K elems per step
#define UNITS 12        // 768/64
#define AELEMS (BM * BKU)              // 12288 elems = 24 KB per slot A-region
#define SLOT_ELEMS ((BM + BN) * BKU)   // 24576 elems = 48 KB
#define THREADS 512
#define XPB 2304        // blocks for x-conversion in prep_all
#define WPB (NP2 / 4)   // 1056 weight blocks

using short8 = __attribute__((ext_vector_type(8))) short;
using f32x4  = __attribute__((ext_vector_type(4))) float;

static __device__ __forceinline__ unsigned short f2bf(float f) {
  union { float f; unsigned int u; } v; v.f = f;
  unsigned int u = v.u;
  unsigned int r = (u + 0x7FFFu + ((u >> 16) & 1u)) >> 16;
  return (unsigned short)r;
}

// ---------------- Fused prep: blocks [0,XPB) convert x -> A (bf16, merged (c,h) K axis);
// blocks [XPB, XPB+WPB) normalize weights -> Qt (bf16, 4224 rows) + wnT (f32 [48][4224]).
__global__ __launch_bounds__(256)
void prep_all(const float* __restrict__ x,
              const float* __restrict__ width,
              const float* __restrict__ height,
              const float* __restrict__ feat,
              unsigned short* __restrict__ A,
              unsigned short* __restrict__ Qt,
              float* __restrict__ wnT) {
  __shared__ float smw[4][WW];
  int bid = blockIdx.x;
  if (bid < XPB) {
    int t = bid * 256 + threadIdx.x;      // XPB*256 == BB*CC*WW*HH/8 exactly
    int e = t * 8;
    int h0 = e % HH;                      // 8 | 48: the 8 elems share (b,c,w)
    int w = (e / HH) % WW;
    int c = (e / (HH * WW)) % CC;
    int b = e / (HH * WW * CC);
    float4 v0 = *(const float4*)(x + e);
    float4 v1 = *(const float4*)(x + e + 4);
    short8 o;
    o[0] = (short)f2bf(v0.x); o[1] = (short)f2bf(v0.y);
    o[2] = (short)f2bf(v0.z); o[3] = (short)f2bf(v0.w);
    o[4] = (short)f2bf(v1.x); o[5] = (short)f2bf(v1.y);
    o[6] = (short)f2bf(v1.z); o[7] = (short)f2bf(v1.w);
    *(short8*)&A[(size_t)(b * WW + w) * KD + c * HH + h0] = o;
  } else {
    int lane = threadIdx.x & 63;
    int wv = threadIdx.x >> 6;            // wave 0..3
    int nbase = (bid - XPB) * 4;
    int n = nbase + wv;                   // 0..4223
    bool valid = (n < OUTD);
    float hv = (valid && lane < HH) ? height[n * HH + lane] : 0.f;
    float wvv = (valid && lane < WW) ? width[n * WW + lane] : 0.f;
    float hs = hv * hv, wsum = wvv * wvv;
    #pragma unroll
    for (int off = 32; off > 0; off >>= 1) {
      hs += __shfl_xor(hs, off);
      wsum += __shfl_xor(wsum, off);
    }
    float hnorm = rsqrtf(hs + EPSF);
    float wnorm = rsqrtf(wsum + EPSF);
    if (lane < WW) smw[wv][lane] = wvv * wnorm;   // 0 for invalid n
    if (valid) {
      #pragma unroll
      for (int i = lane; i < KD; i += 64) {
        int c = i / HH, h = i % HH;
        Qt[(size_t)n * KD + i] = f2bf(feat[n * CC + c] * height[n * HH + h] * hnorm);
      }
    } else {
      #pragma unroll
      for (int i = lane; i < KD; i += 64) Qt[(size_t)n * KD + i] = 0;
    }
    __syncthreads();
    if (threadIdx.x < WW) {
      int w = threadIdx.x;
      float4 o = make_float4(smw[0][w], smw[1][w], smw[2][w], smw[3][w]);
      *(float4*)&wnT[w * NP2 + nbase] = o;
    }
  }
}

// ---------------- Main GEMM: P = A (6144x768) * Qt^T (768x4224), fused w-reduction epilogue.
// m201-faithful 2-phase-per-K-step pipeline: 192x192 tile, 8 waves (2m x 4n), wave tile
// 96x48 (acc 72 + operands 72 regs -- proven-safe profile). Ring-3 LDS (144 KB) enables
// TRULY COUNTED vmcnt(6): at the per-step wait, outstanding = stage(u+1) 6 + stage(u+2) 6,
// wait leaves exactly stage(u+2) in flight. Per phase: reads-before-barrier (phase-B reads
// overlap phase-A MFMA execution), stage-after-barrier, lgkm(0)+sched_barrier, setprio MFMA.
__global__ __launch_bounds__(THREADS, 2)
void gemm_main(const unsigned short* __restrict__ A,   // [6144][768] bf16 bits
               const unsigned short* __restrict__ Qt,  // [4224][768] bf16 bits
               const float* __restrict__ wnT,          // [48][4224]
               const float* __restrict__ bias,         // [4000]
               float* __restrict__ out) {              // [128][4000]
  __shared__ unsigned short S[3 * SLOT_ELEMS];   // 147456 B -> 1 block/CU

  int tid = threadIdx.x;
  int lane = tid & 63;
  int wid = tid >> 6;          // 0..7
  int wm = wid >> 2;           // 0..1 -> 96-row slice
  int wn = wid & 3;            // 0..3 -> 48-col subtile

  // 704 blocks (= 8 XCD x 4 by x 22 bx): XCD k owns by in [4k,4k+4) (A-share 1.18MB,
  // L2-resident), sweeps all 22 bx.
  int bid = blockIdx.x;        // 0..703
  int xcd = bid & 7;
  int idx = bid >> 3;          // 0..87
  int by = xcd * 4 + (idx & 3);   // 0..31
  int bx = idx >> 2;              // 0..21
  int n0 = bx * BN;
  int m0 = by * BM;

  // ---- staging: per wave 3 A-chunks + 3 B-chunks per K-step (chunk: 8 rows x 64 elems
  // = 1KB). LDS dest linear; global source granule XOR-pre-swizzled (granule 16B, row
  // 128B): LDS[row][g*8..] holds global[row][(g ^ (row&7))*8..].
  int rsub = lane >> 3;              // 0..7
  int cg = lane & 7;
  int gsw = (cg ^ rsub) * 8;
  const unsigned short* gA[3];
  const unsigned short* gB[3];
  int aD[3], bD[3];
  #pragma unroll
  for (int j = 0; j < 3; ++j) {
    int c = wid * 3 + j;             // chunk 0..23
    gA[j] = A + (size_t)(m0 + c * 8 + rsub) * KD + gsw;
    gB[j] = Qt + (size_t)(n0 + c * 8 + rsub) * KD + gsw;
    aD[j] = c * 512;
    bD[j] = AELEMS + c * 512;
  }

#define SLOTB(u) (((u) % 3) * SLOT_ELEMS)
#define STAGE_A(u)                                                                \
  { _Pragma("unroll")                                                             \
    for (int j = 0; j < 3; ++j)                                                   \
      __builtin_amdgcn_global_load_lds(                                           \
          (const __attribute__((address_space(1))) void*)(gA[j] + (u) * BKU),     \
          (__attribute__((address_space(3))) void*)(&S[SLOTB(u) + aD[j]]), 16, 0, 0); }
#define STAGE_B(u)                                                                \
  { _Pragma("unroll")                                                             \
    for (int j = 0; j < 3; ++j)                                                   \
      __builtin_amdgcn_global_load_lds(                                           \
          (const __attribute__((address_space(1))) void*)(gB[j] + (u) * BKU),     \
          (__attribute__((address_space(3))) void*)(&S[SLOTB(u) + bD[j]]), 16, 0, 0); }

  // ---- ds_read offsets (elem); rows 64 elems (128B); swizzle matches staging.
  int q16 = lane & 15;
  int hi = lane >> 4;                // 0..3
  int q7 = q16 & 7;
  int arow = (wm * 96 + q16) * BKU;            // + mi*1024 + kgx + SLOTB
  int brow = AELEMS + (wn * 48 + q16) * BKU;   // + ni*1024 + kgx + SLOTB

  f32x4 acc[6][3] = {};              // 72 regs
  short8 af[2][6];
  short8 bf[2][3];

#define DSREAD(set, u, kh)                                              \
  { const unsigned short* sb = &S[SLOTB(u)];                            \
    const int kgx = (((kh) * 4 + hi) ^ q7) * 8;                         \
    _Pragma("unroll")                                                   \
    for (int mi = 0; mi < 6; ++mi)                                      \
      af[set][mi] = *(const short8*)&sb[arow + mi * 1024 + kgx];        \
    _Pragma("unroll")                                                   \
    for (int ni = 0; ni < 3; ++ni)                                      \
      bf[set][ni] = *(const short8*)&sb[brow + ni * 1024 + kgx]; }

#define MFMA18(set)                                                     \
  { _Pragma("unroll")                                                   \
    for (int ni = 0; ni < 3; ++ni)                                      \
      _Pragma("unroll")                                                 \
      for (int mi = 0; mi < 6; ++mi)                                    \
        acc[mi][ni] = __builtin_amdgcn_mfma_f32_16x16x32_bf16(af[set][mi], bf[set][ni], acc[mi][ni], 0, 0, 0); }

  // Prologue: stage steps 0 and 1 (12 loads); publish step 0 (leave step 1's 6 in flight).
  STAGE_A(0); STAGE_B(0);
  STAGE_A(1); STAGE_B(1);
  asm volatile("s_waitcnt vmcnt(6)" ::: "memory");
  __builtin_amdgcn_s_barrier();
  __builtin_amdgcn_sched_barrier(0);

  #pragma unroll
  for (int u = 0; u < UNITS; ++u) {
    // ---- phase A (kh = 0)
    DSREAD(0, u, 0);
    __builtin_amdgcn_sched_barrier(0);
    __builtin_amdgcn_s_barrier();                    // A1
    if (u + 2 < UNITS) STAGE_A(u + 2);               // slot (u+2)%3: readers done per A1
    asm volatile("s_waitcnt lgkmcnt(0)" ::: "memory");
    __builtin_amdgcn_sched_barrier(0);
    __builtin_amdgcn_s_setprio(1);
    MFMA18(0);
    __builtin_amdgcn_s_setprio(0);
    __builtin_amdgcn_sched_barrier(0);
    __builtin_amdgcn_s_barrier();                    // A2
    // ---- phase B (kh = 1): reads overlap phase-A MFMA execution
    DSREAD(1, u, 1);
    __builtin_amdgcn_sched_barrier(0);
    __builtin_amdgcn_s_barrier();                    // B1
    if (u + 2 < UNITS) STAGE_B(u + 2);
    asm volatile("s_waitcnt lgkmcnt(0)" ::: "memory");
    __builtin_amdgcn_sched_barrier(0);
    __builtin_amdgcn_s_setprio(1);
    MFMA18(1);
    __builtin_amdgcn_s_setprio(0);
    __builtin_amdgcn_sched_barrier(0);
    // counted wait publishing step u+1: outstanding = stage(u+1) 6 + stage(u+2) 6
    if (u + 2 < UNITS)       asm volatile("s_waitcnt vmcnt(6)" ::: "memory");
    else if (u + 2 == UNITS) asm volatile("s_waitcnt vmcnt(0)" ::: "memory");
    __builtin_amdgcn_s_barrier();                    // B2: slot u+1 published
    __builtin_amdgcn_sched_barrier(0);
  }

  // ---- Epilogue: y[b,n] = sum_w wnT[w][n] * P[(b,w),n] + bias[n]
  // wave rows: wm*96 + mi*16 + hi*4 + r; batch = by*4 + wm*2 + (mi>=3); w = (mi%3)*16+hi*4+r.
  int b0 = by * 4 + wm * 2;
  #pragma unroll
  for (int ni = 0; ni < 3; ++ni) {
    int ng = n0 + wn * 48 + ni * 16 + q16;
    float s0 = 0.f, s1 = 0.f;
    #pragma unroll
    for (int mi = 0; mi < 3; ++mi) {
      int wbase = mi * 16 + hi * 4;
      f32x4 va = acc[mi][ni];
      f32x4 vb = acc[mi + 3][ni];
      #pragma unroll
      for (int r = 0; r < 4; ++r) {
        float t = wnT[(wbase + r) * NP2 + ng];
        s0 += t * va[r];
        s1 += t * vb[r];
      }
    }
    s0 += __shfl_xor(s0, 16); s0 += __shfl_xor(s0, 32);
    s1 += __shfl_xor(s1, 16); s1 += __shfl_xor(s1, 32);
    if (hi == 0 && ng < OUTD) {
      float bv = bias[ng];
      out[(size_t)b0 * OUTD + ng] = s0 + bv;
      out[(size_t)(b0 + 1) * OUTD + ng] = s1 + bv;
    }
  }
#undef STAGE_A
#undef STAGE_B
#undef SLOTB
#undef DSREAD
#undef MFMA18
}

extern "C" void kernel_launch(void* const* d_in, const int* in_sizes, int n_in,
                              void* d_out, int out_size, void* d_ws, size_t ws_size,
                              hipStream_t stream) {
  const float* x      = (const float*)d_in[0];
  const float* width  = (const float*)d_in[1];
  const float* height = (const float*)d_in[2];
  const float* feat   = (const float*)d_in[3];
  const float* bias   = (const float*)d_in[4];
  float* out = (float*)d_out;

  char* ws = (char*)d_ws;
  unsigned short* A  = (unsigned short*)ws;                        // 6144*768*2  = 9,437,184
  unsigned short* Qt = (unsigned short*)(ws + 9437184);            // 4224*768*2  = 6,488,064
  float* wnT         = (float*)(ws + 9437184 + 6488064);           // 48*4224*4   =   811,008

  prep_all<<<dim3(XPB + WPB), dim3(256), 0, stream>>>(x, width, height, feat, A, Qt, wnT);
  gemm_main<<<dim3(704), dim3(THREADS), 0, stream>>>(A, Qt, wnT, bias, out);
}

// Round 17
// 51.278 us; speedup vs baseline: 1.0940x; 1.0940x over previous
//
#include <hip/hip_runtime.h>
#include <stdint.h>

#define OUTD 4000
#define NPAD 4096
#define CC 16
#define WW 48
#define HH 48
#define BB 128
#define KD 768          // C*H contraction depth
#define MD 6144         // B*W rows
#define EPSF 1e-6f

#define BM 192          // 4 batches * 48 w
#define BNB 256
#define BKU 32          // K elems per unit
#define UNITS 24        // 768/32
#define AELEMS (BM * BKU)              // 6144 elems (12 chunks)
#define SLOT_ELEMS ((BM + BNB) * BKU)  // 14336 elems = 28 KB
#define THREADS 512
#define XPB 2304        // blocks for x-conversion in prep_all

using short8 = __attribute__((ext_vector_type(8))) short;
using f32x4  = __attribute__((ext_vector_type(4))) float;

static __device__ __forceinline__ unsigned short f2bf(float f) {
  union { float f; unsigned int u; } v; v.f = f;
  unsigned int u = v.u;
  unsigned int r = (u + 0x7FFFu + ((u >> 16) & 1u)) >> 16;
  return (unsigned short)r;
}

// ---------------- Fused prep: blocks [0,XPB) convert x -> A (bf16, merged (c,h) K axis);
// blocks [XPB, XPB+1024) normalize weights -> Qt (bf16) + wnT (f32, [48][4096]).
__global__ __launch_bounds__(256)
void prep_all(const float* __restrict__ x,
              const float* __restrict__ width,
              const float* __restrict__ height,
              const float* __restrict__ feat,
              unsigned short* __restrict__ A,
              unsigned short* __restrict__ Qt,
              float* __restrict__ wnT) {
  __shared__ float smw[4][WW];
  int bid = blockIdx.x;
  if (bid < XPB) {
    int t = bid * 256 + threadIdx.x;      // XPB*256 == BB*CC*WW*HH/8 exactly
    int e = t * 8;
    int h0 = e % HH;                      // 8 | 48: the 8 elems share (b,c,w)
    int w = (e / HH) % WW;
    int c = (e / (HH * WW)) % CC;
    int b = e / (HH * WW * CC);
    float4 v0 = *(const float4*)(x + e);
    float4 v1 = *(const float4*)(x + e + 4);
    short8 o;
    o[0] = (short)f2bf(v0.x); o[1] = (short)f2bf(v0.y);
    o[2] = (short)f2bf(v0.z); o[3] = (short)f2bf(v0.w);
    o[4] = (short)f2bf(v1.x); o[5] = (short)f2bf(v1.y);
    o[6] = (short)f2bf(v1.z); o[7] = (short)f2bf(v1.w);
    *(short8*)&A[(size_t)(b * WW + w) * KD + c * HH + h0] = o;
  } else {
    int lane = threadIdx.x & 63;
    int wv = threadIdx.x >> 6;            // wave 0..3
    int nbase = (bid - XPB) * 4;
    int n = nbase + wv;                   // 0..4095
    bool valid = (n < OUTD);
    float hv = (valid && lane < HH) ? height[n * HH + lane] : 0.f;
    float wvv = (valid && lane < WW) ? width[n * WW + lane] : 0.f;
    float hs = hv * hv, wsum = wvv * wvv;
    #pragma unroll
    for (int off = 32; off > 0; off >>= 1) {
      hs += __shfl_xor(hs, off);
      wsum += __shfl_xor(wsum, off);
    }
    float hnorm = rsqrtf(hs + EPSF);
    float wnorm = rsqrtf(wsum + EPSF);
    if (lane < WW) smw[wv][lane] = wvv * wnorm;   // 0 for invalid n
    if (valid) {
      #pragma unroll
      for (int i = lane; i < KD; i += 64) {
        int c = i / HH, h = i % HH;
        Qt[(size_t)n * KD + i] = f2bf(feat[n * CC + c] * height[n * HH + h] * hnorm);
      }
    } else {
      #pragma unroll
      for (int i = lane; i < KD; i += 64) Qt[(size_t)n * KD + i] = 0;
    }
    __syncthreads();
    if (threadIdx.x < WW) {
      int w = threadIdx.x;
      float4 o = make_float4(smw[0][w], smw[1][w], smw[2][w], smw[3][w]);
      *(float4*)&wnT[w * NPAD + nbase] = o;
    }
  }
}

// ---------------- Main GEMM: P = A (6144x768) * Qt^T (768x4096), fused w-reduction epilogue.
// Phase-pipelined m201-style loop at the proven 192x256 / 8-wave / 96x64-wave geometry.
// Ring-4 x 28KB slots (112 KB), stage depth 3, TRULY counted vmcnt(6) (leaves 2 units in
// flight). Per unit 2 phases; next cluster's ds_reads are issued pre-MFMA so they complete
// under the current 12-MFMA cluster. One barrier per unit.
__global__ __launch_bounds__(THREADS, 2)
void gemm_main(const unsigned short* __restrict__ A,   // [6144][768] bf16 bits
               const unsigned short* __restrict__ Qt,  // [4096][768] bf16 bits
               const float* __restrict__ wnT,          // [48][4096]
               const float* __restrict__ bias,         // [4000]
               float* __restrict__ out) {              // [128][4000]
  __shared__ unsigned short S[4 * SLOT_ELEMS];   // 114688 B

  int tid = threadIdx.x;
  int lane = tid & 63;
  int wid = tid >> 6;          // 0..7
  int wm = wid >> 2;           // 0..1 -> 96-row slice
  int wn = wid & 3;            // 0..3 -> 64-col subtile

  // 512 blocks: XCD k (= bid&7) owns by in [4k, 4k+4) (A-share 1.15MB, L2-resident),
  // sweeps 16 bx-groups.
  int bid = blockIdx.x;        // 0..511
  int xcd = bid & 7;
  int i = bid >> 3;            // 0..63
  int by = xcd * 4 + (i & 3);  // 0..31
  int bxg = i >> 2;            // 0..15
  int n0 = bxg * BNB;
  int m0 = by * BM;

  // ---- staging: 28 chunks/unit (chunk: 16 rows x 32 elems = 1KB). A chunks 0..11,
  // B chunks 12..27; LDS chunk base = c*512 uniformly. Wave w owns L in {4,3}:
  // bases 0,4,7,11,14,18,21,25. PART1 = first 2 chunks, PART2 = rest.
  // Global source granule XOR-pre-swizzled (granule 16B, row 64B):
  // LDS[row][g*8..] holds global[row][(g ^ ((row>>1)&3))*8..].
  int lrow = lane >> 2;              // 0..15 row within chunk
  int g = lane & 3;                  // granule
  int gsw = (g ^ ((lrow >> 1) & 3)) * 8;
  const int cbase[8] = {0, 4, 7, 11, 14, 18, 21, 25};
  const int clen[8]  = {4, 3, 4, 3, 4, 3, 4, 3};
  int base = cbase[wid];
  int nl = clen[wid];
  const unsigned short* gp[4];
  int ldst[4];
  #pragma unroll
  for (int j = 0; j < 4; ++j) {
    int c = base + (j < nl ? j : nl - 1);
    gp[j] = (c < 12 ? A + (size_t)(m0 + c * 16 + lrow) * KD
                    : Qt + (size_t)(n0 + (c - 12) * 16 + lrow) * KD) + gsw;
    ldst[j] = c * 512;
  }

#define SLOTB(u) (((u) & 3) * SLOT_ELEMS)
#define STAGE_P1(u)                                                               \
  { _Pragma("unroll")                                                             \
    for (int j = 0; j < 2; ++j)                                                   \
      __builtin_amdgcn_global_load_lds(                                           \
          (const __attribute__((address_space(1))) void*)(gp[j] + (u) * BKU),     \
          (__attribute__((address_space(3))) void*)(&S[SLOTB(u) + ldst[j]]), 16, 0, 0); }
#define STAGE_P2(u)                                                               \
  { _Pragma("unroll")                                                             \
    for (int j = 2; j < 4; ++j)                                                   \
      if (j < nl)                                                                 \
        __builtin_amdgcn_global_load_lds(                                         \
            (const __attribute__((address_space(1))) void*)(gp[j] + (u) * BKU),   \
            (__attribute__((address_space(3))) void*)(&S[SLOTB(u) + ldst[j]]), 16, 0, 0); }

  // ---- ds_read offsets (elem); rows 32 elems (64B); swizzle matches staging.
  int q16 = lane & 15;
  int hi = lane >> 4;                // 0..3 -> k-granule
  int kgr = (hi ^ ((q16 >> 1) & 3)) * 8;
  int arow = (wm * 96 + q16) * BKU + kgr;             // + mi*512
  int brow = AELEMS + (wn * 64 + q16) * BKU + kgr;    // + ni*512

  f32x4 acc[6][4] = {};              // 96 acc regs
  short8 af[2][6];                   // p1-set A frags, double-buffered
  short8 bf[2][4];                   // bf[set][0..1] from p1, [2..3] from ph1

#define DSREAD_P1(set, u)                                               \
  { const unsigned short* sb = &S[SLOTB(u)];                            \
    _Pragma("unroll")                                                   \
    for (int mi = 0; mi < 6; ++mi)                                      \
      af[set][mi] = *(const short8*)&sb[arow + mi * 512];               \
    bf[set][0] = *(const short8*)&sb[brow];                             \
    bf[set][1] = *(const short8*)&sb[brow + 512]; }
#define DSREAD_BF23(set, u)                                             \
  { const unsigned short* sb = &S[SLOTB(u)];                            \
    bf[set][2] = *(const short8*)&sb[brow + 1024];                      \
    bf[set][3] = *(const short8*)&sb[brow + 1536]; }
#define MFMA12(set, nlo)                                                \
  { _Pragma("unroll")                                                   \
    for (int ni = (nlo); ni < (nlo) + 2; ++ni)                          \
      _Pragma("unroll")                                                 \
      for (int mi = 0; mi < 6; ++mi)                                    \
        acc[mi][ni] = __builtin_amdgcn_mfma_f32_16x16x32_bf16(af[set][mi], bf[set][ni], acc[mi][ni], 0, 0, 0); }

  // Prologue: stage units 0..2 (3L loads); publish unit 0 (leave ~2 units in flight).
  STAGE_P1(0); STAGE_P2(0);
  STAGE_P1(1); STAGE_P2(1);
  STAGE_P1(2); STAGE_P2(2);
  asm volatile("s_waitcnt vmcnt(6)" ::: "memory");
  __builtin_amdgcn_s_barrier();
  __builtin_amdgcn_sched_barrier(0);
  DSREAD_P1(0, 0);
  __builtin_amdgcn_sched_barrier(0);

  #pragma unroll
  for (int u = 0; u < UNITS; ++u) {
    const int cs = u & 1, ns = cs ^ 1;
    // ---- phase 1: stage ∥ bf23 read; MFMA ni0-1 (p1-set landed under prior cluster)
    if (u + 3 < UNITS) STAGE_P1(u + 3);
    DSREAD_BF23(cs, u);
    asm volatile("s_waitcnt lgkmcnt(2)" ::: "memory");   // p1-set(u) complete; bf23 in flight
    __builtin_amdgcn_sched_barrier(0);
    __builtin_amdgcn_s_setprio(1);
    MFMA12(cs, 0);
    __builtin_amdgcn_s_setprio(0);
    __builtin_amdgcn_sched_barrier(0);
    // ---- phase 2: publish slot u+1; read its p1-set under MFMA ni2-3
    if (u + 3 < UNITS) STAGE_P2(u + 3);
    if (u + 3 < UNITS)      asm volatile("s_waitcnt vmcnt(6) lgkmcnt(0)" ::: "memory");
    else if (u + 2 < UNITS) asm volatile("s_waitcnt vmcnt(3) lgkmcnt(0)" ::: "memory");
    else if (u + 1 < UNITS) asm volatile("s_waitcnt vmcnt(0) lgkmcnt(0)" ::: "memory");
    else                    asm volatile("s_waitcnt lgkmcnt(0)" ::: "memory");
    __builtin_amdgcn_sched_barrier(0);
    if (u + 1 < UNITS) {
      __builtin_amdgcn_s_barrier();          // slot u+1 published; all reads of slot u-? drained
      DSREAD_P1(ns, u + 1);                  // flies under the MFMA cluster below
    }
    __builtin_amdgcn_sched_barrier(0);
    __builtin_amdgcn_s_setprio(1);
    MFMA12(cs, 2);
    __builtin_amdgcn_s_setprio(0);
    __builtin_amdgcn_sched_barrier(0);
  }

  // ---- Epilogue: y[b,n] = sum_w wnT[w][n] * P[(b,w),n] + bias[n]
  // wave rows: wm*96 + mi*16 + hi*4 + r; batch = by*4 + wm*2 + (mi>=3); w = (mi%3)*16+hi*4+r.
  int b0 = by * 4 + wm * 2;
  #pragma unroll
  for (int ni = 0; ni < 4; ++ni) {
    int ng = n0 + wn * 64 + ni * 16 + q16;
    float s0 = 0.f, s1 = 0.f;
    #pragma unroll
    for (int mi = 0; mi < 3; ++mi) {
      int wbase = mi * 16 + hi * 4;
      f32x4 va = acc[mi][ni];
      f32x4 vb = acc[mi + 3][ni];
      #pragma unroll
      for (int r = 0; r < 4; ++r) {
        float t = wnT[(wbase + r) * NPAD + ng];
        s0 += t * va[r];
        s1 += t * vb[r];
      }
    }
    s0 += __shfl_xor(s0, 16); s0 += __shfl_xor(s0, 32);
    s1 += __shfl_xor(s1, 16); s1 += __shfl_xor(s1, 32);
    if (hi == 0 && ng < OUTD) {
      float bv = bias[ng];
      out[(size_t)b0 * OUTD + ng] = s0 + bv;
      out[(size_t)(b0 + 1) * OUTD + ng] = s1 + bv;
    }
  }
#undef SLOTB
#undef STAGE_P1
#undef STAGE_P2
#undef DSREAD_P1
#undef DSREAD_BF23
#undef MFMA12
}

extern "C" void kernel_launch(void* const* d_in, const int* in_sizes, int n_in,
                              void* d_out, int out_size, void* d_ws, size_t ws_size,
                              hipStream_t stream) {
  const float* x      = (const float*)d_in[0];
  const float* width  = (const float*)d_in[1];
  const float* height = (const float*)d_in[2];
  const float* feat   = (const float*)d_in[3];
  const float* bias   = (const float*)d_in[4];
  float* out = (float*)d_out;

  char* ws = (char*)d_ws;
  unsigned short* A  = (unsigned short*)ws;                        // 6144*768*2 = 9,437,184
  unsigned short* Qt = (unsigned short*)(ws + 9437184);            // 4096*768*2 = 6,291,456
  float* wnT         = (float*)(ws + 9437184 + 6291456);           // 48*4096*4  =   786,432

  prep_all<<<dim3(XPB + NPAD / 4), dim3(256), 0, stream>>>(x, width, height, feat, A, Qt, wnT);
  gemm_main<<<dim3(512), dim3(THREADS), 0, stream>>>(A, Qt, wnT, bias, out);
}

// Round 18
// 49.161 us; speedup vs baseline: 1.1411x; 1.0431x over previous
//
#include <hip/hip_runtime.h>
#include <stdint.h>

#define OUTD 4000
#define NPAD 4096
#define CC 16
#define WW 48
#define HH 48
#define BB 128
#define KD 768          // C*H contraction depth
#define MD 6144         // B*W rows
#define EPSF 1e-6f

#define BM 192          // 4 batches * 48 w
#define BNB 256         // N cols per block
#define BKU 64          // K elems per unit
#define UNITS 12        // 768/64
#define AELEMS (BM * BKU)              // 12288 elems = 24 KB per A slot
#define BELEMS (BNB * BKU)             // 16384 elems = 32 KB per B slot
#define SLOTE (AELEMS + BELEMS)        // 28672 elems = 56 KB per slot
#define THREADS 512
#define XPB 1152        // blocks for x-conversion (16 elems/thread)

using short8  = __attribute__((ext_vector_type(8))) short;
using short16 = __attribute__((ext_vector_type(16))) short;
using f32x4   = __attribute__((ext_vector_type(4))) float;

static __device__ __forceinline__ unsigned short f2bf(float f) {
  union { float f; unsigned int u; } v; v.f = f;
  unsigned int u = v.u;
  unsigned int r = (u + 0x7FFFu + ((u >> 16) & 1u)) >> 16;
  return (unsigned short)r;
}

// ---------------- Fused prep: blocks [0,XPB) convert x -> A (bf16, merged (c,h) K axis,
// 16 elems/thread); blocks [XPB, XPB+1024) normalize weights -> Qt (bf16) + wnT (f32).
__global__ __launch_bounds__(256)
void prep_all(const float* __restrict__ x,
              const float* __restrict__ width,
              const float* __restrict__ height,
              const float* __restrict__ feat,
              unsigned short* __restrict__ A,
              unsigned short* __restrict__ Qt,
              float* __restrict__ wnT) {
  __shared__ float smw[4][WW];
  int bid = blockIdx.x;
  if (bid < XPB) {
    int t = bid * 256 + threadIdx.x;      // XPB*256*16 == BB*CC*WW*HH exactly
    int e = t * 16;
    int h0 = e % HH;                      // 16 | 48: the 16 elems share (b,c,w)
    int w = (e / HH) % WW;
    int c = (e / (HH * WW)) % CC;
    int b = e / (HH * WW * CC);
    float4 v0 = *(const float4*)(x + e);
    float4 v1 = *(const float4*)(x + e + 4);
    float4 v2 = *(const float4*)(x + e + 8);
    float4 v3 = *(const float4*)(x + e + 12);
    short16 o;
    o[0]  = (short)f2bf(v0.x); o[1]  = (short)f2bf(v0.y);
    o[2]  = (short)f2bf(v0.z); o[3]  = (short)f2bf(v0.w);
    o[4]  = (short)f2bf(v1.x); o[5]  = (short)f2bf(v1.y);
    o[6]  = (short)f2bf(v1.z); o[7]  = (short)f2bf(v1.w);
    o[8]  = (short)f2bf(v2.x); o[9]  = (short)f2bf(v2.y);
    o[10] = (short)f2bf(v2.z); o[11] = (short)f2bf(v2.w);
    o[12] = (short)f2bf(v3.x); o[13] = (short)f2bf(v3.y);
    o[14] = (short)f2bf(v3.z); o[15] = (short)f2bf(v3.w);
    *(short16*)&A[(size_t)(b * WW + w) * KD + c * HH + h0] = o;
  } else {
    int lane = threadIdx.x & 63;
    int wv = threadIdx.x >> 6;            // wave 0..3
    int nbase = (bid - XPB) * 4;
    int n = nbase + wv;                   // 0..4095
    bool valid = (n < OUTD);
    float hv = (valid && lane < HH) ? height[n * HH + lane] : 0.f;
    float wvv = (valid && lane < WW) ? width[n * WW + lane] : 0.f;
    float hs = hv * hv, wsum = wvv * wvv;
    #pragma unroll
    for (int off = 32; off > 0; off >>= 1) {
      hs += __shfl_xor(hs, off);
      wsum += __shfl_xor(wsum, off);
    }
    float hnorm = rsqrtf(hs + EPSF);
    float wnorm = rsqrtf(wsum + EPSF);
    if (lane < WW) smw[wv][lane] = wvv * wnorm;   // 0 for invalid n
    if (valid) {
      #pragma unroll
      for (int i = lane; i < KD; i += 64) {
        int c = i / HH, h = i % HH;
        Qt[(size_t)n * KD + i] = f2bf(feat[n * CC + c] * height[n * HH + h] * hnorm);
      }
    } else {
      #pragma unroll
      for (int i = lane; i < KD; i += 64) Qt[(size_t)n * KD + i] = 0;
    }
    __syncthreads();
    if (threadIdx.x < WW) {
      int w = threadIdx.x;
      float4 o = make_float4(smw[0][w], smw[1][w], smw[2][w], smw[3][w]);
      *(float4*)&wnT[w * NPAD + nbase] = o;
    }
  }
}

// ---------------- Main GEMM: P = A (6144x768) * Qt^T (768x4096), fused w-reduction epilogue.
// Best-measured structure (round-12): 192x256 block, 8 waves (2m x 4n), wave tile 96x64
// (acc 96 regs -- the proven no-spill profile). 2-slot ring (112 KB LDS), one barrier/unit,
// counted vmcnt(7) with 1-unit DMA lead; both k-half ds_reads front-loaded so k-half-1
// completes under the k-half-0 MFMA cluster. ~950 TF effective; plain-HIP plateau for
// this shape (w-aligned epilogue pins BM to 96k; 128-VGPR cap pins acc<=96; ring-3 at
// 56KB slots exceeds the 160KB LDS pool -- the >1.5PF configs are mutually excluded).
__global__ __launch_bounds__(THREADS, 2)
void gemm_main(const unsigned short* __restrict__ A,   // [6144][768] bf16 bits
               const unsigned short* __restrict__ Qt,  // [4096][768] bf16 bits
               const float* __restrict__ wnT,          // [48][4096]
               const float* __restrict__ bias,         // [4000]
               float* __restrict__ out) {              // [128][4000]
  __shared__ unsigned short S[2 * SLOTE];   // 114688 B

  int tid = threadIdx.x;
  int lane = tid & 63;
  int wid = tid >> 6;          // 0..7
  int wm = wid >> 2;           // 0..1 -> 96-row slice
  int wn = wid & 3;            // 0..3 -> 64-col subtile

  // 512 blocks: XCD k (= bid&7) owns by in [4k, 4k+4) (A-share 1.15MB, L2-resident),
  // sweeps 16 bx-groups.
  int bid = blockIdx.x;        // 0..511
  int xcd = bid & 7;
  int i = bid >> 3;            // 0..63
  int by = xcd * 4 + (i & 3);  // 0..31
  int bxg = i >> 2;            // 0..15
  int n0 = bxg * BNB;
  int m0 = by * BM;

  // ---- staging: A 3 chunks + B 4 chunks per wave per unit (chunk: 8 rows x 64 elems = 1KB).
  // LDS dest linear; global source granule XOR-pre-swizzled (granule 16B, row 128B):
  // LDS[row][g*8..] holds global[row][(g ^ (row&7))*8..].
  int rsub = lane >> 3;              // 0..7
  int cg = lane & 7;
  int gsw = (cg ^ rsub) * 8;
  const unsigned short* gA[3];
  const unsigned short* gB[4];
  #pragma unroll
  for (int j = 0; j < 3; ++j)
    gA[j] = A + (size_t)(m0 + (wid * 3 + j) * 8 + rsub) * KD + gsw;
  #pragma unroll
  for (int j = 0; j < 4; ++j)
    gB[j] = Qt + (size_t)(n0 + (wid * 4 + j) * 8 + rsub) * KD + gsw;
  int aD[3], bD[4];
  #pragma unroll
  for (int j = 0; j < 3; ++j) aD[j] = (wid * 3 + j) * 512;
  #pragma unroll
  for (int j = 0; j < 4; ++j) bD[j] = AELEMS + (wid * 4 + j) * 512;

#define SLOTB(u) (((u) & 1) * SLOTE)
#define STAGE(u)                                                                    \
  { _Pragma("unroll")                                                               \
    for (int j = 0; j < 3; ++j)                                                     \
      __builtin_amdgcn_global_load_lds(                                             \
          (const __attribute__((address_space(1))) void*)(gA[j] + (u) * BKU),       \
          (__attribute__((address_space(3))) void*)(&S[SLOTB(u) + aD[j]]), 16, 0, 0); \
    _Pragma("unroll")                                                               \
    for (int j = 0; j < 4; ++j)                                                     \
      __builtin_amdgcn_global_load_lds(                                             \
          (const __attribute__((address_space(1))) void*)(gB[j] + (u) * BKU),       \
          (__attribute__((address_space(3))) void*)(&S[SLOTB(u) + bD[j]]), 16, 0, 0); }

  // ---- ds_read offsets (elem); rows 64 elems (128B); swizzle matches staging.
  int q16 = lane & 15;
  int hi = lane >> 4;                // 0..3
  int q7 = q16 & 7;
  int kg0 = ((0 * 4 + hi) ^ q7) * 8;
  int kg1 = ((1 * 4 + hi) ^ q7) * 8;
  int arow = (wm * 96 + q16) * BKU;              // + mi*16*64 + kg + SLOTB
  int brow = AELEMS + (wn * 64 + q16) * BKU;     // + ni*16*64 + kg + SLOTB

  f32x4 acc[6][4] = {};
  short8 afA[6], bfA[4], afB[6], bfB[4];

#define DSREAD_H(afX, bfX, u, kg)                                      \
  { const unsigned short* sb = &S[SLOTB(u)];                           \
    _Pragma("unroll")                                                  \
    for (int mi = 0; mi < 6; ++mi)                                     \
      afX[mi] = *(const short8*)&sb[arow + mi * 16 * BKU + (kg)];      \
    _Pragma("unroll")                                                  \
    for (int ni = 0; ni < 4; ++ni)                                     \
      bfX[ni] = *(const short8*)&sb[brow + ni * 16 * BKU + (kg)]; }

#define MFMA24(afX, bfX)                                               \
  { _Pragma("unroll")                                                  \
    for (int ni = 0; ni < 4; ++ni)                                     \
      _Pragma("unroll")                                                \
      for (int mi = 0; mi < 6; ++mi)                                   \
        acc[mi][ni] = __builtin_amdgcn_mfma_f32_16x16x32_bf16(afX[mi], bfX[ni], acc[mi][ni], 0, 0, 0); }

  // Prologue: stage unit 0.
  STAGE(0);

  #pragma unroll
  for (int u = 0; u < UNITS; ++u) {
    if (u + 1 < UNITS) {
      STAGE(u + 1);                            // 7 loads -> other slot (1-unit DMA lead)
      asm volatile("s_waitcnt vmcnt(7)" ::: "memory");   // unit u's 7 landed; u+1's stay in flight
    } else {
      asm volatile("s_waitcnt vmcnt(0)" ::: "memory");
    }
    __builtin_amdgcn_s_barrier();              // all waves: slot u ready
    __builtin_amdgcn_sched_barrier(0);

    DSREAD_H(afA, bfA, u, kg0);                // k-half 0 reads (exposed burst)
    asm volatile("s_waitcnt lgkmcnt(0)" ::: "memory");
    __builtin_amdgcn_sched_barrier(0);
    DSREAD_H(afB, bfB, u, kg1);                // k-half 1 reads: complete under MFMA0
    __builtin_amdgcn_s_setprio(1);
    MFMA24(afA, bfA);
    asm volatile("s_waitcnt lgkmcnt(0)" ::: "memory");
    __builtin_amdgcn_sched_barrier(0);
    MFMA24(afB, bfB);
    __builtin_amdgcn_s_setprio(0);
    __builtin_amdgcn_sched_barrier(0);
    // each wave's slot-u reads are lgkm-drained before its MFMA cluster ends, which
    // precedes barrier(u+1), which precedes STAGE(u+2) overwriting slot u.
  }

  // ---- Epilogue: y[b,n] = sum_w wnT[w][n] * P[(b,w),n] + bias[n]
  // wave rows: wm*96 + mi*16 + hi*4 + rr; batch = by*4 + wm*2 + (mi>=3); w = (mi%3)*16+hi*4+rr.
  int b0 = by * 4 + wm * 2;
  #pragma unroll
  for (int ni = 0; ni < 4; ++ni) {
    int ng = n0 + wn * 64 + ni * 16 + q16;
    float s0 = 0.f, s1 = 0.f;
    #pragma unroll
    for (int mi = 0; mi < 3; ++mi) {
      int wbase = mi * 16 + hi * 4;
      f32x4 va = acc[mi][ni];
      f32x4 vb = acc[mi + 3][ni];
      #pragma unroll
      for (int r = 0; r < 4; ++r) {
        float t = wnT[(wbase + r) * NPAD + ng];
        s0 += t * va[r];
        s1 += t * vb[r];
      }
    }
    s0 += __shfl_xor(s0, 16); s0 += __shfl_xor(s0, 32);
    s1 += __shfl_xor(s1, 16); s1 += __shfl_xor(s1, 32);
    if (hi == 0 && ng < OUTD) {
      float bv = bias[ng];
      out[(size_t)b0 * OUTD + ng] = s0 + bv;
      out[(size_t)(b0 + 1) * OUTD + ng] = s1 + bv;
    }
  }
#undef STAGE
#undef SLOTB
#undef DSREAD_H
#undef MFMA24
}

extern "C" void kernel_launch(void* const* d_in, const int* in_sizes, int n_in,
                              void* d_out, int out_size, void* d_ws, size_t ws_size,
                              hipStream_t stream) {
  const float* x      = (const float*)d_in[0];
  const float* width  = (const float*)d_in[1];
  const float* height = (const float*)d_in[2];
  const float* feat   = (const float*)d_in[3];
  const float* bias   = (const float*)d_in[4];
  float* out = (float*)d_out;

  char* ws = (char*)d_ws;
  unsigned short* A  = (unsigned short*)ws;                        // 6144*768*2 = 9,437,184
  unsigned short* Qt = (unsigned short*)(ws + 9437184);            // 4096*768*2 = 6,291,456
  float* wnT         = (float*)(ws + 9437184 + 6291456);           // 48*4096*4  =   786,432

  prep_all<<<dim3(XPB + NPAD / 4), dim3(256), 0, stream>>>(x, width, height, feat, A, Qt, wnT);
  gemm_main<<<dim3(512), dim3(THREADS), 0, stream>>>(A, Qt, wnT, bias, out);
}

// Round 19
// 48.827 us; speedup vs baseline: 1.1489x; 1.0068x over previous
//
#include <hip/hip_runtime.h>
#include <stdint.h>

#define OUTD 4000
#define NPAD 4096
#define CC 16
#define WW 48
#define HH 48
#define BB 128
#define KD 768          // C*H contraction depth
#define MD 6144         // B*W rows
#define EPSF 1e-6f

#define BM 192          // 4 batches * 48 w
#define BNB 256         // N cols per block
#define BKU 64          // K elems per unit
#define UNITS 12        // 768/64
#define AELEMS (BM * BKU)              // 12288 elems = 24 KB per A slot
#define BELEMS (BNB * BKU)             // 16384 elems = 32 KB per B slot
#define SLOTE (AELEMS + BELEMS)        // 28672 elems = 56 KB per slot
#define THREADS 512
#define XPB 1152        // blocks for x-conversion (16 elems/thread)

using short8  = __attribute__((ext_vector_type(8))) short;
using short16 = __attribute__((ext_vector_type(16))) short;
using f32x4   = __attribute__((ext_vector_type(4))) float;

static __device__ __forceinline__ unsigned short f2bf(float f) {
  union { float f; unsigned int u; } v; v.f = f;
  unsigned int u = v.u;
  unsigned int r = (u + 0x7FFFu + ((u >> 16) & 1u)) >> 16;
  return (unsigned short)r;
}

// ---------------- Fused prep: blocks [0,XPB) convert x -> A (bf16, merged (c,h) K axis,
// 16 elems/thread); blocks [XPB, XPB+1024) normalize weights -> Qt (bf16) + wnT (f32).
__global__ __launch_bounds__(256)
void prep_all(const float* __restrict__ x,
              const float* __restrict__ width,
              const float* __restrict__ height,
              const float* __restrict__ feat,
              unsigned short* __restrict__ A,
              unsigned short* __restrict__ Qt,
              float* __restrict__ wnT) {
  __shared__ float smw[4][WW];
  int bid = blockIdx.x;
  if (bid < XPB) {
    int t = bid * 256 + threadIdx.x;      // XPB*256*16 == BB*CC*WW*HH exactly
    int e = t * 16;
    int h0 = e % HH;                      // 16 | 48: the 16 elems share (b,c,w)
    int w = (e / HH) % WW;
    int c = (e / (HH * WW)) % CC;
    int b = e / (HH * WW * CC);
    float4 v0 = *(const float4*)(x + e);
    float4 v1 = *(const float4*)(x + e + 4);
    float4 v2 = *(const float4*)(x + e + 8);
    float4 v3 = *(const float4*)(x + e + 12);
    short16 o;
    o[0]  = (short)f2bf(v0.x); o[1]  = (short)f2bf(v0.y);
    o[2]  = (short)f2bf(v0.z); o[3]  = (short)f2bf(v0.w);
    o[4]  = (short)f2bf(v1.x); o[5]  = (short)f2bf(v1.y);
    o[6]  = (short)f2bf(v1.z); o[7]  = (short)f2bf(v1.w);
    o[8]  = (short)f2bf(v2.x); o[9]  = (short)f2bf(v2.y);
    o[10] = (short)f2bf(v2.z); o[11] = (short)f2bf(v2.w);
    o[12] = (short)f2bf(v3.x); o[13] = (short)f2bf(v3.y);
    o[14] = (short)f2bf(v3.z); o[15] = (short)f2bf(v3.w);
    *(short16*)&A[(size_t)(b * WW + w) * KD + c * HH + h0] = o;
  } else {
    int lane = threadIdx.x & 63;
    int wv = threadIdx.x >> 6;            // wave 0..3
    int nbase = (bid - XPB) * 4;
    int n = nbase + wv;                   // 0..4095
    bool valid = (n < OUTD);
    float hv = (valid && lane < HH) ? height[n * HH + lane] : 0.f;
    float wvv = (valid && lane < WW) ? width[n * WW + lane] : 0.f;
    float hs = hv * hv, wsum = wvv * wvv;
    #pragma unroll
    for (int off = 32; off > 0; off >>= 1) {
      hs += __shfl_xor(hs, off);
      wsum += __shfl_xor(wsum, off);
    }
    float hnorm = rsqrtf(hs + EPSF);
    float wnorm = rsqrtf(wsum + EPSF);
    if (lane < WW) smw[wv][lane] = wvv * wnorm;   // 0 for invalid n
    if (valid) {
      #pragma unroll
      for (int i = lane; i < KD; i += 64) {
        int c = i / HH, h = i % HH;
        Qt[(size_t)n * KD + i] = f2bf(feat[n * CC + c] * height[n * HH + h] * hnorm);
      }
    } else {
      #pragma unroll
      for (int i = lane; i < KD; i += 64) Qt[(size_t)n * KD + i] = 0;
    }
    __syncthreads();
    if (threadIdx.x < WW) {
      int w = threadIdx.x;
      float4 o = make_float4(smw[0][w], smw[1][w], smw[2][w], smw[3][w]);
      *(float4*)&wnT[w * NPAD + nbase] = o;
    }
  }
}

// ---------------- Main GEMM: P = A (6144x768) * Qt^T (768x4096), fused w-reduction epilogue.
// Best-measured structure (round-12) + counted-lgkm fix: all 20 ds_reads issued up front,
// lgkmcnt(10) gates MFMA-A (k-half-1 reads complete UNDER it), lgkmcnt(0) gates MFMA-B.
// Removes the fully-exposed k-half-0 drain (~320-500 cyc/unit) of the r12 body.
// 192x256 block, 8 waves (2m x 4n), wave tile 96x64 (acc 96 -- proven no-spill profile),
// 2-slot ring (112 KB LDS), one barrier/unit, counted vmcnt(7) with 1-unit DMA lead.
__global__ __launch_bounds__(THREADS, 2)
void gemm_main(const unsigned short* __restrict__ A,   // [6144][768] bf16 bits
               const unsigned short* __restrict__ Qt,  // [4096][768] bf16 bits
               const float* __restrict__ wnT,          // [48][4096]
               const float* __restrict__ bias,         // [4000]
               float* __restrict__ out) {              // [128][4000]
  __shared__ unsigned short S[2 * SLOTE];   // 114688 B

  int tid = threadIdx.x;
  int lane = tid & 63;
  int wid = tid >> 6;          // 0..7
  int wm = wid >> 2;           // 0..1 -> 96-row slice
  int wn = wid & 3;            // 0..3 -> 64-col subtile

  // 512 blocks: XCD k (= bid&7) owns by in [4k, 4k+4) (A-share 1.15MB, L2-resident),
  // sweeps 16 bx-groups.
  int bid = blockIdx.x;        // 0..511
  int xcd = bid & 7;
  int i = bid >> 3;            // 0..63
  int by = xcd * 4 + (i & 3);  // 0..31
  int bxg = i >> 2;            // 0..15
  int n0 = bxg * BNB;
  int m0 = by * BM;

  // ---- staging: A 3 chunks + B 4 chunks per wave per unit (chunk: 8 rows x 64 elems = 1KB).
  // LDS dest linear; global source granule XOR-pre-swizzled (granule 16B, row 128B):
  // LDS[row][g*8..] holds global[row][(g ^ (row&7))*8..].
  int rsub = lane >> 3;              // 0..7
  int cg = lane & 7;
  int gsw = (cg ^ rsub) * 8;
  const unsigned short* gA[3];
  const unsigned short* gB[4];
  #pragma unroll
  for (int j = 0; j < 3; ++j)
    gA[j] = A + (size_t)(m0 + (wid * 3 + j) * 8 + rsub) * KD + gsw;
  #pragma unroll
  for (int j = 0; j < 4; ++j)
    gB[j] = Qt + (size_t)(n0 + (wid * 4 + j) * 8 + rsub) * KD + gsw;
  int aD[3], bD[4];
  #pragma unroll
  for (int j = 0; j < 3; ++j) aD[j] = (wid * 3 + j) * 512;
  #pragma unroll
  for (int j = 0; j < 4; ++j) bD[j] = AELEMS + (wid * 4 + j) * 512;

#define SLOTB(u) (((u) & 1) * SLOTE)
#define STAGE(u)                                                                    \
  { _Pragma("unroll")                                                               \
    for (int j = 0; j < 3; ++j)                                                     \
      __builtin_amdgcn_global_load_lds(                                             \
          (const __attribute__((address_space(1))) void*)(gA[j] + (u) * BKU),       \
          (__attribute__((address_space(3))) void*)(&S[SLOTB(u) + aD[j]]), 16, 0, 0); \
    _Pragma("unroll")                                                               \
    for (int j = 0; j < 4; ++j)                                                     \
      __builtin_amdgcn_global_load_lds(                                             \
          (const __attribute__((address_space(1))) void*)(gB[j] + (u) * BKU),       \
          (__attribute__((address_space(3))) void*)(&S[SLOTB(u) + bD[j]]), 16, 0, 0); }

  // ---- ds_read offsets (elem); rows 64 elems (128B); swizzle matches staging.
  int q16 = lane & 15;
  int hi = lane >> 4;                // 0..3
  int q7 = q16 & 7;
  int kg0 = ((0 * 4 + hi) ^ q7) * 8;
  int kg1 = ((1 * 4 + hi) ^ q7) * 8;
  int arow = (wm * 96 + q16) * BKU;              // + mi*16*64 + kg + SLOTB
  int brow = AELEMS + (wn * 64 + q16) * BKU;     // + ni*16*64 + kg + SLOTB

  f32x4 acc[6][4] = {};
  short8 afA[6], bfA[4], afB[6], bfB[4];

#define DSREAD_H(afX, bfX, u, kg)                                      \
  { const unsigned short* sb = &S[SLOTB(u)];                           \
    _Pragma("unroll")                                                  \
    for (int mi = 0; mi < 6; ++mi)                                     \
      afX[mi] = *(const short8*)&sb[arow + mi * 16 * BKU + (kg)];      \
    _Pragma("unroll")                                                  \
    for (int ni = 0; ni < 4; ++ni)                                     \
      bfX[ni] = *(const short8*)&sb[brow + ni * 16 * BKU + (kg)]; }

#define MFMA24(afX, bfX)                                               \
  { _Pragma("unroll")                                                  \
    for (int ni = 0; ni < 4; ++ni)                                     \
      _Pragma("unroll")                                                \
      for (int mi = 0; mi < 6; ++mi)                                   \
        acc[mi][ni] = __builtin_amdgcn_mfma_f32_16x16x32_bf16(afX[mi], bfX[ni], acc[mi][ni], 0, 0, 0); }

  // Prologue: stage unit 0.
  STAGE(0);

  #pragma unroll
  for (int u = 0; u < UNITS; ++u) {
    if (u + 1 < UNITS) {
      STAGE(u + 1);                            // 7 loads -> other slot (1-unit DMA lead)
      asm volatile("s_waitcnt vmcnt(7)" ::: "memory");   // unit u's 7 landed; u+1's stay in flight
    } else {
      asm volatile("s_waitcnt vmcnt(0)" ::: "memory");
    }
    __builtin_amdgcn_s_barrier();              // all waves: slot u ready
    __builtin_amdgcn_sched_barrier(0);

    DSREAD_H(afA, bfA, u, kg0);                // k-half 0 reads (10)
    DSREAD_H(afB, bfB, u, kg1);                // k-half 1 reads (10) -- issued immediately
    asm volatile("s_waitcnt lgkmcnt(10)" ::: "memory");  // k-half 0 landed; k-half 1 in flight
    __builtin_amdgcn_sched_barrier(0);
    __builtin_amdgcn_s_setprio(1);
    MFMA24(afA, bfA);                          // k-half-1 reads complete under this cluster
    __builtin_amdgcn_s_setprio(0);
    asm volatile("s_waitcnt lgkmcnt(0)" ::: "memory");
    __builtin_amdgcn_sched_barrier(0);
    __builtin_amdgcn_s_setprio(1);
    MFMA24(afB, bfB);
    __builtin_amdgcn_s_setprio(0);
    __builtin_amdgcn_sched_barrier(0);
    // each wave's slot-u reads are lgkm-drained before its MFMA cluster ends, which
    // precedes barrier(u+1), which precedes STAGE(u+2) overwriting slot u.
  }

  // ---- Epilogue: y[b,n] = sum_w wnT[w][n] * P[(b,w),n] + bias[n]
  // wave rows: wm*96 + mi*16 + hi*4 + rr; batch = by*4 + wm*2 + (mi>=3); w = (mi%3)*16+hi*4+rr.
  int b0 = by * 4 + wm * 2;
  #pragma unroll
  for (int ni = 0; ni < 4; ++ni) {
    int ng = n0 + wn * 64 + ni * 16 + q16;
    float s0 = 0.f, s1 = 0.f;
    #pragma unroll
    for (int mi = 0; mi < 3; ++mi) {
      int wbase = mi * 16 + hi * 4;
      f32x4 va = acc[mi][ni];
      f32x4 vb = acc[mi + 3][ni];
      #pragma unroll
      for (int r = 0; r < 4; ++r) {
        float t = wnT[(wbase + r) * NPAD + ng];
        s0 += t * va[r];
        s1 += t * vb[r];
      }
    }
    s0 += __shfl_xor(s0, 16); s0 += __shfl_xor(s0, 32);
    s1 += __shfl_xor(s1, 16); s1 += __shfl_xor(s1, 32);
    if (hi == 0 && ng < OUTD) {
      float bv = bias[ng];
      out[(size_t)b0 * OUTD + ng] = s0 + bv;
      out[(size_t)(b0 + 1) * OUTD + ng] = s1 + bv;
    }
  }
#undef STAGE
#undef SLOTB
#undef DSREAD_H
#undef MFMA24
}

extern "C" void kernel_launch(void* const* d_in, const int* in_sizes, int n_in,
                              void* d_out, int out_size, void* d_ws, size_t ws_size,
                              hipStream_t stream) {
  const float* x      = (const float*)d_in[0];
  const float* width  = (const float*)d_in[1];
  const float* height = (const float*)d_in[2];
  const float* feat   = (const float*)d_in[3];
  const float* bias   = (const float*)d_in[4];
  float* out = (float*)d_out;

  char* ws = (char*)d_ws;
  unsigned short* A  = (unsigned short*)ws;                        // 6144*768*2 = 9,437,184
  unsigned short* Qt = (unsigned short*)(ws + 9437184);            // 4096*768*2 = 6,291,456
  float* wnT         = (float*)(ws + 9437184 + 6291456);           // 48*4096*4  =   786,432

  prep_all<<<dim3(XPB + NPAD / 4), dim3(256), 0, stream>>>(x, width, height, feat, A, Qt, wnT);
  gemm_main<<<dim3(512), dim3(THREADS), 0, stream>>>(A, Qt, wnT, bias, out);
}